// Round 9
// baseline (542.990 us; speedup 1.0000x reference)
//
#include <hip/hip_runtime.h>
#include <hip/hip_bf16.h>
#include <stdint.h>

#define IN_F 4096
#define OUT_F 4096
#define MTOK 8192
#define TOPX_N 10
#define NUMVALS 200000
#define CSR_BLOCKS ((NUMVALS + 255) / 256)
#define CVT_BLOCKS ((MTOK * IN_F / 8) / 256)   /* 16384 */

typedef __bf16 bf16x8 __attribute__((ext_vector_type(8)));
typedef float f32x4 __attribute__((ext_vector_type(4)));

__device__ __forceinline__ void gld_lds16(const void* g, void* l) {
    __builtin_amdgcn_global_load_lds((const __attribute__((address_space(1))) void*)g,
                                     (__attribute__((address_space(3))) void*)l, 16, 0, 0);
}

// ---------------------------------------------------------------------------
// 1) Dequant: W^T[j][k] = lut[j][code(k,j)], bf16, layout (OUT_F, IN_F).
// ---------------------------------------------------------------------------
__global__ __launch_bounds__(256) void k_dequant(const int* __restrict__ qw,
                                                 const float* __restrict__ lut,
                                                 __bf16* __restrict__ Wt) {
    __shared__ int qs[64 * 65];
    __shared__ float ls[64 * 16];
    const int b = blockIdx.x;
    const int jc = (b & 63) * 64;
    const int wc = (b >> 6) * 64;
    const int t = threadIdx.x;

    {
        float4 v = *(const float4*)(lut + (size_t)(jc + (t >> 2)) * 16 + (t & 3) * 4);
        *(float4*)(ls + (t >> 2) * 16 + (t & 3) * 4) = v;
    }
#pragma unroll
    for (int p = 0; p < 4; ++p) {
        int idx = t + p * 256;
        int row = idx >> 4;
        int c4 = (idx & 15) * 4;
        int4 v = *(const int4*)(qw + (size_t)(wc + row) * OUT_F + jc + c4);
        int base = row * 65 + c4;
        qs[base] = v.x; qs[base + 1] = v.y; qs[base + 2] = v.z; qs[base + 3] = v.w;
    }
    __syncthreads();

    const int wave = t >> 6, lane = t & 63;
#pragma unroll
    for (int i = 0; i < 16; ++i) {
        const int c = wave * 16 + i;
        const unsigned q = (unsigned)qs[lane * 65 + c];
        const float* lp = ls + c * 16;
        bf16x8 v;
#pragma unroll
        for (int e = 0; e < 8; ++e) v[e] = (__bf16)lp[(q >> (4 * e)) & 15];
        *(bf16x8*)(Wt + (size_t)(jc + c) * IN_F + (size_t)(wc + lane) * 8) = v;
    }
}

// ---------------------------------------------------------------------------
// 2) Fused prep: x fp32->bf16 convert + CSR outliers + topX (one dispatch).
// ---------------------------------------------------------------------------
__device__ __forceinline__ void bf16_cas_add(__bf16* Wt, size_t elem, float v) {
    unsigned* wp = (unsigned*)Wt + (elem >> 1);
    unsigned sh = (unsigned)(elem & 1) * 16;
    unsigned old = *wp, assumed;
    do {
        assumed = old;
        union { unsigned u; float f; } cv;
        cv.u = ((assumed >> sh) & 0xFFFFu) << 16;      // bf16 -> f32 (exact)
        __bf16 nb = (__bf16)(cv.f + v);
        unsigned nh = *(unsigned short*)&nb;
        unsigned newv = (assumed & ~(0xFFFFu << sh)) | ((unsigned)nh << sh);
        old = atomicCAS(wp, assumed, newv);
    } while (old != assumed);
}

__global__ __launch_bounds__(256) void k_prep(const float* __restrict__ x,
                                              __bf16* __restrict__ xb,
                                              const int* __restrict__ rows,
                                              const int* __restrict__ cols,
                                              const float* __restrict__ vals,
                                              const float* __restrict__ fr,
                                              const int* __restrict__ fri,
                                              __bf16* __restrict__ Wt) {
    const int b = blockIdx.x;
    if (b < CVT_BLOCKS) {
        size_t t = (size_t)b * 256 + threadIdx.x;
        const float4* p = (const float4*)x + 2 * t;
        float4 a = p[0], c = p[1];
        bf16x8 v;
        v[0] = (__bf16)a.x; v[1] = (__bf16)a.y; v[2] = (__bf16)a.z; v[3] = (__bf16)a.w;
        v[4] = (__bf16)c.x; v[5] = (__bf16)c.y; v[6] = (__bf16)c.z; v[7] = (__bf16)c.w;
        ((bf16x8*)xb)[t] = v;
    } else if (b < CVT_BLOCKS + CSR_BLOCKS) {
        int n = (b - CVT_BLOCKS) * 256 + threadIdx.x;
        if (n >= NUMVALS) return;
        int lo = 0, hi = OUT_F + 1;
        while (lo < hi) {
            int mid = (lo + hi) >> 1;
            if (rows[mid] <= n) lo = mid + 1; else hi = mid;
        }
        int r = lo - 1;
        bf16_cas_add(Wt, (size_t)r * IN_F + cols[n], vals[n]);
    } else {
        int i = (b - CVT_BLOCKS - CSR_BLOCKS) * 256 + threadIdx.x;
        if (i >= IN_F) return;
#pragma unroll
        for (int t = 0; t < TOPX_N; ++t) {
            int j = fri[t];
            bf16_cas_add(Wt, (size_t)j * IN_F + i, fr[(size_t)i * TOPX_N + t]);
        }
    }
}

// ---------------------------------------------------------------------------
// 3) GEMM — R6 4-buffer ring + REGISTER-FRAGMENT DOUBLE BUFFER.
//    Diagnosis (R7/R8, model closes on counters): per K-tile per CU the DS
//    read burst (~1150 cyc) and the MFMA stream (~1242 cyc) run serially,
//    because fragments are read and consumed inside the same barrier
//    window (true dependency -> lgkm wait; both waves/SIMD in same phase).
//    Fix: prefetch tile t+1's 12 fragments into a SECOND register set
//    right after barrier(t) (tile t+1 guaranteed in LDS by counted vmcnt),
//    consume them after barrier(t+1). Tile t's MFMAs have no pending
//    ds_reads to wait on -> DS pipe and matrix pipe co-run.
//    WAR: prefetch-reads of buffer b (iter t) are lgkm-drained before each
//    wave's MFMAs of iter t+1, hence before barrier(t+2); STAGE overwrites
//    b only after barrier(t+2) (4-ring, stage depth t+3). vmcnt(4) at each
//    boundary = only newest stage (tile t+2) outstanding; tile t+1 landed.
//    Regs: 24 frags x4 + 128 acc ~= 240 VGPR (2 waves/SIMD ok; tripwire
//    at 256/spill).
//
//    T2 swizzle (0 conflicts measured): (r,g) at slot ((5r+g)&7)+8g+32(r>>3);
//    DMA dest linear, global source inverse-swizzled, reads swizzled.
// ---------------------------------------------------------------------------
#define BK_G 32
#define NKT (IN_F / BK_G)          /* 128 K-tiles */
#define TILE_BYTES 16384           /* 256 rows x 64 B */
#define MFMA_ __builtin_amdgcn_mfma_f32_16x16x32_bf16
#define SB0 __builtin_amdgcn_sched_barrier(0)
#define VMC4  asm volatile("s_waitcnt vmcnt(4)" ::: "memory")
#define VMC0  asm volatile("s_waitcnt vmcnt(0)" ::: "memory")
#define BARF  do { __builtin_amdgcn_s_barrier(); asm volatile("" ::: "memory"); } while (0)
#define ROT(x) ((x) == 98304 ? 0 : (x) + 32768)

__global__ __launch_bounds__(512, 2) void k_gemm(const __bf16* __restrict__ A,
                                                 const __bf16* __restrict__ Bt,
                                                 const float* __restrict__ bias,
                                                 float* __restrict__ C) {
    __shared__ __align__(1024) char smem[4][2][TILE_BYTES];   // [buf][A/B][tile] = 128 KiB
    char* const sm = (char*)smem;

    const int tid = threadIdx.x;
    const int wave = tid >> 6, lane = tid & 63;
    const int wm = wave >> 2, wn = wave & 3;

    // XCD-aware swizzle: 512 blocks, 8 XCDs, 64 contiguous per XCD (n-fast).
    const int bid = blockIdx.x;
    const int swz = (bid & 7) * 64 + (bid >> 3);
    const int n0 = (swz & 15) * 256;
    const int m0 = (swz >> 4) * 256;

    // ---- staging map: lane -> (row_local, granule) it must fetch ----
    const int q = lane & 7, g = (lane >> 3) & 3, rh = lane >> 5;
    const int rloc = ((5 * (q - g + 8)) & 7) + 8 * rh;   // 0..15
    const int w0 = wave * 2;                             // this wave's 2 windows

    const char* gA0 = (const char*)(A  + (size_t)(m0 + w0 * 16 + rloc) * IN_F) + g * 16;
    const char* gA1 = gA0 + 16 * IN_F * 2;
    const char* gB0 = (const char*)(Bt + (size_t)(n0 + w0 * 16 + rloc) * IN_F) + g * 16;
    const char* gB1 = gB0 + 16 * IN_F * 2;
    char* lA = (char*)smem[0][0] + w0 * 1024;            // + boff selects buffer
    char* lB = (char*)smem[0][1] + w0 * 1024;

    // ---- read map: frag (row = wbase + m*16 + lrow, granule kk) ----
    const int lrow = lane & 15, kk = lane >> 4;
    const int rdc = ((5 * lrow + kk) & 7) * 16 + kk * 128 + (lrow >> 3) * 512;
    const int rdA = wm * 8192 + rdc;                     // + m*1024 immediate
    const int rdB = 16384 + wn * 4096 + rdc;             // + n*1024 immediate

#define STAGE(boff, koff) do {                               \
        gld_lds16(gA0 + (koff), lA + (boff));                \
        gld_lds16(gA1 + (koff), lA + (boff) + 1024);         \
        gld_lds16(gB0 + (koff), lB + (boff));                \
        gld_lds16(gB1 + (koff), lB + (boff) + 1024);         \
    } while (0)

    // Prefetch tile fragments into a register set (no consumer this window).
#define RD(af_, bf_, boff) do {                                                  \
        const char* pA = sm + (boff) + rdA;                                      \
        const char* pB = sm + (boff) + rdB;                                      \
        _Pragma("unroll") for (int n = 0; n < 4; ++n)                            \
            bf_[n] = *(const bf16x8*)(pB + n * 1024);                            \
        _Pragma("unroll") for (int m = 0; m < 8; ++m)                            \
            af_[m] = *(const bf16x8*)(pA + m * 1024);                            \
    } while (0)

#define CMP(af_, bf_) do {                                                       \
        __builtin_amdgcn_s_setprio(1);                                           \
        _Pragma("unroll") for (int m = 0; m < 8; ++m)                            \
            _Pragma("unroll") for (int n = 0; n < 4; ++n)                        \
                acc[m][n] = MFMA_(af_[m], bf_[n], acc[m][n], 0, 0, 0);           \
        __builtin_amdgcn_s_setprio(0);                                           \
    } while (0)

    f32x4 acc[8][4] = {};
    bf16x8 afA[8], bfA[4], afB[8], bfB[4];

    // ---- prologue: stage tiles 0,1,2; wait tile 0; prefetch tile 0 ----
    STAGE(0, 0);
    STAGE(32768, 64);
    STAGE(65536, 128);
    asm volatile("s_waitcnt vmcnt(8)" ::: "memory");
    BARF;
    RD(afA, bfA, 0);
    SB0;

    int rboff = 32768;   // buffer holding tile t+1 (read target)
    int sboff = 98304;   // buffer receiving tile t+3 (stage target)

    // t = 0..125 (2-unrolled); each iter: wait tile t+1, stage t+3,
    // prefetch t+1 into the idle reg set, compute tile t from the live set.
    for (int h = 0; h < 63; ++h) {
        // ---- t = 2h (even): compute A, prefetch into B ----
        VMC4; BARF;
        STAGE(sboff, (2 * h + 3) * 64);          // t<=124 always here
        RD(afB, bfB, rboff);
        SB0;
        CMP(afA, bfA);
        rboff = ROT(rboff); sboff = ROT(sboff);
        // ---- t = 2h+1 (odd): compute B, prefetch into A ----
        VMC4; BARF;
        if (h < 62) STAGE(sboff, (2 * h + 4) * 64);
        RD(afA, bfA, rboff);
        SB0;
        CMP(afB, bfB);
        rboff = ROT(rboff); sboff = ROT(sboff);
    }
    // ---- t = 126: last prefetch (tile 127) ----
    VMC0; BARF;
    RD(afB, bfB, rboff);
    SB0;
    CMP(afA, bfA);
    // ---- t = 127 ----
    CMP(afB, bfB);

    // ---- epilogue: C/D layout col = lane&15, row = (lane>>4)*4 + r ----
    const int m0w = m0 + wm * 128;
    const int n0w = n0 + wn * 64;
#pragma unroll
    for (int n = 0; n < 4; ++n) {
        const int col = n0w + n * 16 + lrow;
        const float bj = bias[col];
#pragma unroll
        for (int m = 0; m < 8; ++m) {
            const int row = m0w + m * 16 + kk * 4;
#pragma unroll
            for (int r = 0; r < 4; ++r)
                C[(size_t)(row + r) * OUT_F + col] = acc[m][n][r] + bj;
        }
    }
#undef STAGE
#undef RD
#undef CMP
}

extern "C" void kernel_launch(void* const* d_in, const int* in_sizes, int n_in,
                              void* d_out, int out_size, void* d_ws, size_t ws_size,
                              hipStream_t stream) {
    const float* x         = (const float*)d_in[0];
    const int*   qweight   = (const int*)d_in[1];
    const float* lut       = (const float*)d_in[2];
    const float* bias      = (const float*)d_in[3];
    const int*   rows      = (const int*)d_in[4];
    const int*   cols      = (const int*)d_in[5];
    const float* vals      = (const float*)d_in[6];
    const float* full_rows = (const float*)d_in[7];
    const int*   fri       = (const int*)d_in[8];
    float* out = (float*)d_out;

    __bf16* Wt = (__bf16*)d_ws;                                        // 32 MB: W^T (OUT_F, IN_F)
    __bf16* xb = (__bf16*)((char*)d_ws + (size_t)OUT_F * IN_F * 2);    // 64 MB: x bf16 (8192, 4096)

    k_dequant<<<dim3(64 * 8), 256, 0, stream>>>(qweight, lut, Wt);
    k_prep<<<dim3(CVT_BLOCKS + CSR_BLOCKS + IN_F / 256), 256, 0, stream>>>(
        x, xb, rows, cols, vals, full_rows, fri, Wt);
    k_gemm<<<dim3((OUT_F / 256) * (MTOK / 256)), 512, 0, stream>>>(xb, Wt, bias, out);
}

// Round 11
// 514.794 us; speedup vs baseline: 1.0548x; 1.0548x over previous
//
#include <hip/hip_runtime.h>
#include <hip/hip_bf16.h>
#include <stdint.h>

#define IN_F 4096
#define OUT_F 4096
#define MTOK 8192
#define TOPX_N 10
#define NUMVALS 200000
#define CSR_BLOCKS ((NUMVALS + 255) / 256)
#define CVT_BLOCKS ((MTOK * IN_F / 8) / 256)   /* 16384 */

typedef __bf16 bf16x8 __attribute__((ext_vector_type(8)));
typedef float f32x4 __attribute__((ext_vector_type(4)));
typedef float fvec4 __attribute__((ext_vector_type(4)));   // native vec for nt builtins

__device__ __forceinline__ void gld_lds16(const void* g, void* l) {
    __builtin_amdgcn_global_load_lds((const __attribute__((address_space(1))) void*)g,
                                     (__attribute__((address_space(3))) void*)l, 16, 0, 0);
}

// ---------------------------------------------------------------------------
// 1) Dequant: W^T[j][k] = lut[j][code(k,j)], bf16, layout (OUT_F, IN_F).
// ---------------------------------------------------------------------------
__global__ __launch_bounds__(256) void k_dequant(const int* __restrict__ qw,
                                                 const float* __restrict__ lut,
                                                 __bf16* __restrict__ Wt) {
    __shared__ int qs[64 * 65];
    __shared__ float ls[64 * 16];
    const int b = blockIdx.x;
    const int jc = (b & 63) * 64;
    const int wc = (b >> 6) * 64;
    const int t = threadIdx.x;

    {
        float4 v = *(const float4*)(lut + (size_t)(jc + (t >> 2)) * 16 + (t & 3) * 4);
        *(float4*)(ls + (t >> 2) * 16 + (t & 3) * 4) = v;
    }
#pragma unroll
    for (int p = 0; p < 4; ++p) {
        int idx = t + p * 256;
        int row = idx >> 4;
        int c4 = (idx & 15) * 4;
        int4 v = *(const int4*)(qw + (size_t)(wc + row) * OUT_F + jc + c4);
        int base = row * 65 + c4;
        qs[base] = v.x; qs[base + 1] = v.y; qs[base + 2] = v.z; qs[base + 3] = v.w;
    }
    __syncthreads();

    const int wave = t >> 6, lane = t & 63;
#pragma unroll
    for (int i = 0; i < 16; ++i) {
        const int c = wave * 16 + i;
        const unsigned q = (unsigned)qs[lane * 65 + c];
        const float* lp = ls + c * 16;
        bf16x8 v;
#pragma unroll
        for (int e = 0; e < 8; ++e) v[e] = (__bf16)lp[(q >> (4 * e)) & 15];
        *(bf16x8*)(Wt + (size_t)(jc + c) * IN_F + (size_t)(wc + lane) * 8) = v;
    }
}

// ---------------------------------------------------------------------------
// 2) Fused prep: x fp32->bf16 convert + CSR outliers + topX (one dispatch).
//    x loads are NON-TEMPORAL (read-once 128 MB; keep it out of L2/L3 so
//    the GEMM's A/B operand set stays resident). nt builtins need a native
//    clang vector type, not HIP_vector_type (R10 compile fix).
// ---------------------------------------------------------------------------
__device__ __forceinline__ void bf16_cas_add(__bf16* Wt, size_t elem, float v) {
    unsigned* wp = (unsigned*)Wt + (elem >> 1);
    unsigned sh = (unsigned)(elem & 1) * 16;
    unsigned old = *wp, assumed;
    do {
        assumed = old;
        union { unsigned u; float f; } cv;
        cv.u = ((assumed >> sh) & 0xFFFFu) << 16;      // bf16 -> f32 (exact)
        __bf16 nb = (__bf16)(cv.f + v);
        unsigned nh = *(unsigned short*)&nb;
        unsigned newv = (assumed & ~(0xFFFFu << sh)) | ((unsigned)nh << sh);
        old = atomicCAS(wp, assumed, newv);
    } while (old != assumed);
}

__global__ __launch_bounds__(256) void k_prep(const float* __restrict__ x,
                                              __bf16* __restrict__ xb,
                                              const int* __restrict__ rows,
                                              const int* __restrict__ cols,
                                              const float* __restrict__ vals,
                                              const float* __restrict__ fr,
                                              const int* __restrict__ fri,
                                              __bf16* __restrict__ Wt) {
    const int b = blockIdx.x;
    if (b < CVT_BLOCKS) {
        size_t t = (size_t)b * 256 + threadIdx.x;
        const fvec4* p = (const fvec4*)x + 2 * t;
        fvec4 a = __builtin_nontemporal_load(p);
        fvec4 c = __builtin_nontemporal_load(p + 1);
        bf16x8 v;
        v[0] = (__bf16)a[0]; v[1] = (__bf16)a[1]; v[2] = (__bf16)a[2]; v[3] = (__bf16)a[3];
        v[4] = (__bf16)c[0]; v[5] = (__bf16)c[1]; v[6] = (__bf16)c[2]; v[7] = (__bf16)c[3];
        ((bf16x8*)xb)[t] = v;
    } else if (b < CVT_BLOCKS + CSR_BLOCKS) {
        int n = (b - CVT_BLOCKS) * 256 + threadIdx.x;
        if (n >= NUMVALS) return;
        int lo = 0, hi = OUT_F + 1;
        while (lo < hi) {
            int mid = (lo + hi) >> 1;
            if (rows[mid] <= n) lo = mid + 1; else hi = mid;
        }
        int r = lo - 1;
        bf16_cas_add(Wt, (size_t)r * IN_F + cols[n], vals[n]);
    } else {
        int i = (b - CVT_BLOCKS - CSR_BLOCKS) * 256 + threadIdx.x;
        if (i >= IN_F) return;
#pragma unroll
        for (int t = 0; t < TOPX_N; ++t) {
            int j = fri[t];
            bf16_cas_add(Wt, (size_t)j * IN_F + i, fr[(size_t)i * TOPX_N + t]);
        }
    }
}

// ---------------------------------------------------------------------------
// 3) GEMM — R6 4-buffer ring (verified 297 us) + NON-TEMPORAL C STORES.
//    R9's register-double-buffer null (MFMAs with zero pending lgkm still
//    ~300 us) falsified the schedule-bound model. Re-diagnosis: staged LDS
//    traffic is 1.5 GB logical; FETCH_SIZE 300 MB => ~1.2 GB served by
//    L2/L3 at only ~4 TB/s effective — the binding constraint. Suspect:
//    the 128 MB write-once C stream evicts resident A/B stripes from the
//    4 MB per-XCD L2s (32 blocks/XCD x 256 KB epilogue bursts = 8 MB) and
//    churns L3. Fix: nt stores for C (no L2/L3 allocation). Schedule
//    structure is FROZEN (R2/R4/R7/R8/R9 all regressed or null vs this).
//
//    T2 swizzle (0 conflicts measured): (r,g) at slot ((5r+g)&7)+8g+32(r>>3);
//    DMA dest linear, global source inverse-swizzled, reads swizzled.
// ---------------------------------------------------------------------------
#define BK_G 32
#define NKT (IN_F / BK_G)          /* 128 K-tiles */
#define TILE_BYTES 16384           /* 256 rows x 64 B */
#define MFMA_ __builtin_amdgcn_mfma_f32_16x16x32_bf16

__global__ __launch_bounds__(512, 2) void k_gemm(const __bf16* __restrict__ A,
                                                 const __bf16* __restrict__ Bt,
                                                 const float* __restrict__ bias,
                                                 float* __restrict__ C) {
    __shared__ __align__(1024) char smem[4][2][TILE_BYTES];   // [buf][A/B][tile] = 128 KiB

    const int tid = threadIdx.x;
    const int wave = tid >> 6, lane = tid & 63;
    const int wm = wave >> 2, wn = wave & 3;

    // XCD-aware swizzle: 512 blocks, 8 XCDs, 64 contiguous per XCD (n-fast).
    const int bid = blockIdx.x;
    const int swz = (bid & 7) * 64 + (bid >> 3);
    const int n0 = (swz & 15) * 256;
    const int m0 = (swz >> 4) * 256;

    // ---- staging map: lane -> (row_local, granule) it must fetch ----
    const int q = lane & 7, g = (lane >> 3) & 3, rh = lane >> 5;
    const int rloc = ((5 * (q - g + 8)) & 7) + 8 * rh;   // 0..15
    const int w0 = wave * 2;                             // this wave's 2 windows

    const char* gA0 = (const char*)(A  + (size_t)(m0 + w0 * 16 + rloc) * IN_F) + g * 16;
    const char* gA1 = gA0 + 16 * IN_F * 2;
    const char* gB0 = (const char*)(Bt + (size_t)(n0 + w0 * 16 + rloc) * IN_F) + g * 16;
    const char* gB1 = gB0 + 16 * IN_F * 2;
    char* lA = (char*)smem[0][0] + w0 * 1024;            // + boff selects buffer
    char* lB = (char*)smem[0][1] + w0 * 1024;

    // ---- read map: frag (row = wbase + m*16 + lrow, granule kk) ----
    const int lrow = lane & 15, kk = lane >> 4;
    const int rdc = ((5 * lrow + kk) & 7) * 16 + kk * 128 + (lrow >> 3) * 512;
    const int rdA = wm * 8192 + rdc;                     // + m*1024 immediate
    const int rdB = wn * 4096 + rdc;                     // + n*1024 immediate

#define STAGE(boff, koff) do {                               \
        gld_lds16(gA0 + (koff), lA + (boff));                \
        gld_lds16(gA1 + (koff), lA + (boff) + 1024);         \
        gld_lds16(gB0 + (koff), lB + (boff));                \
        gld_lds16(gB1 + (koff), lB + (boff) + 1024);         \
    } while (0)

#define COMPUTE(boff) do {                                                                     \
        const char* pA = (const char*)smem[0][0] + (boff) + rdA;                               \
        const char* pB = (const char*)smem[0][1] + (boff) + rdB;                               \
        bf16x8 bfr[4], af0[4], af1[4];                                                         \
        _Pragma("unroll") for (int n = 0; n < 4; ++n) bfr[n] = *(const bf16x8*)(pB + n * 1024);\
        _Pragma("unroll") for (int m = 0; m < 4; ++m) af0[m] = *(const bf16x8*)(pA + m * 1024);\
        _Pragma("unroll") for (int m = 0; m < 4; ++m) af1[m] = *(const bf16x8*)(pA + 4096 + m * 1024);\
        __builtin_amdgcn_s_setprio(1);                                                         \
        _Pragma("unroll") for (int m = 0; m < 4; ++m)                                          \
            _Pragma("unroll") for (int n = 0; n < 4; ++n)                                      \
                acc[m][n] = MFMA_(af0[m], bfr[n], acc[m][n], 0, 0, 0);                         \
        _Pragma("unroll") for (int m = 0; m < 4; ++m)                                          \
            _Pragma("unroll") for (int n = 0; n < 4; ++n)                                      \
                acc[m + 4][n] = MFMA_(af1[m], bfr[n], acc[m + 4][n], 0, 0, 0);                 \
        __builtin_amdgcn_s_setprio(0);                                                         \
    } while (0)

    f32x4 acc[8][4] = {};

    // prologue: tiles 0,1,2 -> bufs 0,1,2 (12 loads in flight)
    STAGE(0, 0);
    STAGE(32768, 64);
    STAGE(65536, 128);

    int cboff = 0, sboff = 98304;
    for (int t = 0; t < NKT - 2; ++t) {
        // tile t landed (tiles t+1, t+2 = 8 loads may remain in flight)
        asm volatile("s_waitcnt vmcnt(8)" ::: "memory");
        __builtin_amdgcn_s_barrier();
        asm volatile("" ::: "memory");     // keep stage/ds_reads below the barrier
        if (t + 3 < NKT) STAGE(sboff, (t + 3) * 64);
        COMPUTE(cboff);
        cboff = cboff == 98304 ? 0 : cboff + 32768;
        sboff = sboff == 98304 ? 0 : sboff + 32768;
    }
    // tile NKT-2: 8 loads outstanding; need the oldest 4 (this tile) landed
    asm volatile("s_waitcnt vmcnt(4)" ::: "memory");
    __builtin_amdgcn_s_barrier();
    asm volatile("" ::: "memory");
    COMPUTE(cboff);
    cboff = cboff == 98304 ? 0 : cboff + 32768;
    // tile NKT-1: drain
    asm volatile("s_waitcnt vmcnt(0)" ::: "memory");
    __builtin_amdgcn_s_barrier();
    asm volatile("" ::: "memory");
    COMPUTE(cboff);

    // ---- epilogue: nt stores (C is write-once; do not evict A/B from L2/L3) ----
    const int m0w = m0 + wm * 128;
    const int n0w = n0 + wn * 64;
#pragma unroll
    for (int n = 0; n < 4; ++n) {
        const int col = n0w + n * 16 + lrow;
        const float bj = bias[col];
#pragma unroll
        for (int m = 0; m < 8; ++m) {
            const int row = m0w + m * 16 + kk * 4;
#pragma unroll
            for (int r = 0; r < 4; ++r)
                __builtin_nontemporal_store(acc[m][n][r] + bj,
                                            &C[(size_t)(row + r) * OUT_F + col]);
        }
    }
#undef STAGE
#undef COMPUTE
}

extern "C" void kernel_launch(void* const* d_in, const int* in_sizes, int n_in,
                              void* d_out, int out_size, void* d_ws, size_t ws_size,
                              hipStream_t stream) {
    const float* x         = (const float*)d_in[0];
    const int*   qweight   = (const int*)d_in[1];
    const float* lut       = (const float*)d_in[2];
    const float* bias      = (const float*)d_in[3];
    const int*   rows      = (const int*)d_in[4];
    const int*   cols      = (const int*)d_in[5];
    const float* vals      = (const float*)d_in[6];
    const float* full_rows = (const float*)d_in[7];
    const int*   fri       = (const int*)d_in[8];
    float* out = (float*)d_out;

    __bf16* Wt = (__bf16*)d_ws;                                        // 32 MB: W^T (OUT_F, IN_F)
    __bf16* xb = (__bf16*)((char*)d_ws + (size_t)OUT_F * IN_F * 2);    // 64 MB: x bf16 (8192, 4096)

    k_dequant<<<dim3(64 * 8), 256, 0, stream>>>(qweight, lut, Wt);
    k_prep<<<dim3(CVT_BLOCKS + CSR_BLOCKS + IN_F / 256), 256, 0, stream>>>(
        x, xb, rows, cols, vals, full_rows, fri, Wt);
    k_gemm<<<dim3((OUT_F / 256) * (MTOK / 256)), 512, 0, stream>>>(xb, Wt, bias, out);
}